// Round 10
// baseline (416.264 us; speedup 1.0000x reference)
//
#include <hip/hip_runtime.h>

#define NT 256          // f(x) table size
#define NBATCH 1024
#define NOUT 65536      // 1024*64

#if __has_builtin(__builtin_amdgcn_exp2f)
#define EXP2(x) __builtin_amdgcn_exp2f(x)
#else
#define EXP2(x) exp2f(x)
#endif

// ---- graph constants (baked from the reference) ----
__constant__ int c_e1[17] = {0,0,1,2,2,3,4,5,6,8,8,9,10,11,11,13,14};
__constant__ int c_e2[17] = {1,4,2,3,5,4,12,6,7,9,12,10,11,12,13,14,15};
__constant__ int c_p0[24] = {1,0,1,1,3,2,0,0,3,2,5,5,9,8,9,10,10,12,4,4,8,11,13,13};
__constant__ int c_p1[24] = {4,2,3,5,5,4,3,12,12,6,7,6,12,10,11,11,13,13,8,11,11,14,15,14};
__constant__ int c_ni[24] = {0,1,2,2,2,3,4,4,4,5,6,7,8,9,10,11,11,11,12,12,12,13,14,15};

// 6 unordered products (a<=b). E_ab symmetric => ovl = W + W^T,
// W = sum pref_ab * C_a E_ab C_b^T  (diagonal gets pref/2, folded into exp arg).
__constant__ int c_pa[6]   = {0,0,0,1,1,2};
__constant__ int c_pb[6]   = {0,1,2,1,2,2};
__constant__ int c_diag[6] = {1,0,0,1,0,1};

// ---- kernel 0: materialize C' (opposite-blocks transform) to global ----
// ctg[s][j][q] = CT row-major 8 floats per (s,j). Batch-invariant: V-phase
// reads it via wave-uniform scalar loads (off the LDS pipe).
__global__ void k_prep(const float* __restrict__ cg, float* __restrict__ ctg) {
  const int idx = blockIdx.x * 256 + threadIdx.x;
  if (idx < 3 * 81 * 8) {
    const int s = idx / 648;
    const int rem = idx - s * 648;
    const int j = rem >> 3, q = rem & 7;
    const int col = s * 81 + j;
    const int off = j - 33;
    float v;
    if (off >= 0 && (off & 1)) v = -cg[q * 243 + (col - 1)];
    else                       v =  cg[q * 243 + col];
    ctg[idx] = v;
  }
}

// ---- kernel 1: per-batch W; ovl = W + W^T ----
// v10 V-phase: lane = output row. Wave-task = (product s, row-half h);
// 12 tasks/block, 3 per wave (wt = wave*3+it). pA in registers, CT from
// GLOBAL via readfirstlane-scalarized pointer (LDS pipe freed), only
// P4[j] broadcast remains on LDS. 8 NAMED scalar accumulators
// (arrays => scratch demotion, r4-r7).
__global__ __launch_bounds__(256, 6)
void k_ovl(const float* __restrict__ pos, const float* __restrict__ cg,
           const float* __restrict__ sigp, const float* __restrict__ ctg,
           float* __restrict__ xout, float* __restrict__ bmin,
           float* __restrict__ bmax) {
  // manual smem (floats): posS[48] | P4[81][4] | CT[3][81][8] (stage-2) |
  // Vall[6][81][8] | cInv[6] cLgp[6]  == 6216 floats = 24.9 KB
  __shared__ __align__(16) float smem[6216];
  float* posS          = smem;                                // [48]
  float (*P4)[4]       = (float(*)[4])    (smem + 48);        // [81][4]
  float (*CT)[81][8]   = (float(*)[81][8])(smem + 372);       // [3][81][8]
  float (*Vall)[81][8] = (float(*)[81][8])(smem + 2316);      // [6][81][8]
  float* cInv          = smem + 6204;                         // [6]
  float* cLgp          = smem + 6210;                         // [6]
  float (*red4)[64]    = (float(*)[64])   (smem + 2316);      // ALIAS of Vall
  // (red4 written only after stage-2 finishes reading Vall; barrier-separated)

  const int b = blockIdx.x;
  const int t = threadIdx.x;
  const int wv = t >> 6;
  const int lane = t & 63;

  if (t < 48) posS[t] = pos[b * 48 + t];

  // CT in LDS for stage-2's per-lane reads (same transform as k_prep)
  for (int idx = t; idx < 3 * 81 * 8; idx += 256) {
    int s = idx / 648;
    int rem = idx - s * 648;
    int j = rem >> 3, q = rem & 7;
    int col = s * 81 + j;
    int off = j - 33;
    float v;
    if (off >= 0 && (off & 1)) v = -cg[q * 243 + (col - 1)];
    else                       v =  cg[q * 243 + col];
    CT[s][j][q] = v;
  }

  if (t == 0) {
    float sg[3];
    sg[0] = 0.4f * __expf(sigp[0]);
    sg[1] = 0.8f * __expf(sigp[1]);
    sg[2] = 1.2f * __expf(sigp[2]);
    #pragma unroll
    for (int p = 0; p < 6; ++p) {
      float sa = sg[c_pa[p]], sb = sg[c_pb[p]];
      float s2 = sa * sa + sb * sb;
      float rr = 2.0f * sa * sb / s2;
      cLgp[p] = 1.5f * __log2f(rr) - (float)c_diag[p];  // diag: pref/2
      cInv[p] = (-0.5f / s2) * 1.44269504088896f;       // includes log2(e)
    }
  }
  __syncthreads();

  // 81 block points: 16 atoms, 17 bond midpoints, 24 pairs x 2 cross points
  if (t < 81) {
    float x, y, z;
    if (t < 16) {
      x = posS[t * 3]; y = posS[t * 3 + 1]; z = posS[t * 3 + 2];
    } else if (t < 33) {
      int e = t - 16;
      int a0 = c_e1[e] * 3, a1 = c_e2[e] * 3;
      x = 0.5f * (posS[a0] + posS[a1]);
      y = 0.5f * (posS[a0 + 1] + posS[a1 + 1]);
      z = 0.5f * (posS[a0 + 2] + posS[a1 + 2]);
    } else {
      int k = (t - 33) >> 1, sgn = (t - 33) & 1;
      float sc = sgn ? 0.25f : -0.25f;
      int n = c_ni[k] * 3, a0 = c_p0[k] * 3, a1 = c_p1[k] * 3;
      x = posS[n]     + sc * (posS[a0]     - posS[a1]);
      y = posS[n + 1] + sc * (posS[a0 + 1] - posS[a1 + 1]);
      z = posS[n + 2] + sc * (posS[a0 + 2] - posS[a1 + 2]);
    }
    P4[t][0] = x; P4[t][1] = y; P4[t][2] = z;
    P4[t][3] = x * x + y * y + z * z;
  }
  __syncthreads();

  // ---- V phase: 12 wave-tasks = (product s, half h); lane = row ----
  for (int it = 0; it < 3; ++it) {
    const int wt = wv * 3 + it;                        // 0..11
    const int s  = __builtin_amdgcn_readfirstlane(wt >> 1);
    const int h  = wt & 1;
    const int i  = h * 64 + lane;
    const float nInv = cInv[s];
    const float lgp  = cLgp[s];
    const float m2 = -2.0f * nInv;
    const float* __restrict__ ctp = ctg + c_pb[s] * 648;   // scalar base

    if (i < 81) {
      const float4 pA = *(const float4*)P4[i];
      const float cA = fmaf(pA.w, nInv, lgp);

      float v0=0,v1=0,v2=0,v3=0,v4=0,v5=0,v6=0,v7=0;

      // singles: atoms + bond midpoints (j = 0..32)
      for (int j = 0; j < 33; ++j) {
        const float4 pj = *(const float4*)P4[j];
        const float d = pA.x * pj.x + pA.y * pj.y + pA.z * pj.z;
        const float e = EXP2(fmaf(m2, d, fmaf(pj.w, nInv, cA)));
        const float4 cb0 = *(const float4*)(ctp + j * 8);
        const float4 cb1 = *(const float4*)(ctp + j * 8 + 4);
        v0 = fmaf(e, cb0.x, v0); v1 = fmaf(e, cb0.y, v1);
        v2 = fmaf(e, cb0.z, v2); v3 = fmaf(e, cb0.w, v3);
        v4 = fmaf(e, cb1.x, v4); v5 = fmaf(e, cb1.y, v5);
        v6 = fmaf(e, cb1.z, v6); v7 = fmaf(e, cb1.w, v7);
      }

      // cross pairs: j+ = 33+2k (ct), j- = j+ + 1 (-ct): (e+ - e-)*ct
      for (int k = 0; k < 24; ++k) {
        const int jp = 33 + (k << 1);
        const float4 pp = *(const float4*)P4[jp];
        const float4 pm = *(const float4*)P4[jp + 1];
        const float dp = pA.x * pp.x + pA.y * pp.y + pA.z * pp.z;
        const float dm = pA.x * pm.x + pA.y * pm.y + pA.z * pm.z;
        const float g = EXP2(fmaf(m2, dp, fmaf(pp.w, nInv, cA)))
                      - EXP2(fmaf(m2, dm, fmaf(pm.w, nInv, cA)));
        const float4 cb0 = *(const float4*)(ctp + jp * 8);
        const float4 cb1 = *(const float4*)(ctp + jp * 8 + 4);
        v0 = fmaf(g, cb0.x, v0); v1 = fmaf(g, cb0.y, v1);
        v2 = fmaf(g, cb0.z, v2); v3 = fmaf(g, cb0.w, v3);
        v4 = fmaf(g, cb1.x, v4); v5 = fmaf(g, cb1.y, v5);
        v6 = fmaf(g, cb1.z, v6); v7 = fmaf(g, cb1.w, v7);
      }

      float4* vo = (float4*)&Vall[s][i][0];
      vo[0] = make_float4(v0, v1, v2, v3);
      vo[1] = make_float4(v4, v5, v6, v7);
    }
  }
  __syncthreads();

  // ---- stage 2: W[p][q] = sum_s sum_i CT[pa[s]][i][p] * Vall[s][i][q]
  // 128 threads = 8p x 2 q-quads x 8 i-chunks; Vall read as float4.
  float o0 = 0.0f, o1 = 0.0f, o2 = 0.0f, o3 = 0.0f;
  if (t < 128) {
    const int p = t >> 4;
    const int qg = (t >> 3) & 1;
    const int ch = t & 7;
    const int ib = ch * 10;
    const int ie = (ch == 7) ? 81 : ib + 10;
    #pragma unroll
    for (int s = 0; s < 6; ++s) {
      const int lf = c_pa[s];
      for (int i = ib; i < ie; ++i) {
        const float ct = CT[lf][i][p];
        const float4 vv = *(const float4*)&Vall[s][i][qg * 4];
        o0 = fmaf(ct, vv.x, o0); o1 = fmaf(ct, vv.y, o1);
        o2 = fmaf(ct, vv.z, o2); o3 = fmaf(ct, vv.w, o3);
      }
    }
  }
  __syncthreads();   // all Vall reads done; red4 (alias of Vall) now writable
  if (t < 128) {
    const int p = t >> 4;
    const int qg = (t >> 3) & 1;
    const int ch = t & 7;
    red4[ch][p * 8 + qg * 4 + 0] = o0;
    red4[ch][p * 8 + qg * 4 + 1] = o1;
    red4[ch][p * 8 + qg * 4 + 2] = o2;
    red4[ch][p * 8 + qg * 4 + 3] = o3;
  }
  __syncthreads();

  if (t < 64) {
    float ws = 0.0f;
    #pragma unroll
    for (int ch = 0; ch < 8; ++ch) ws += red4[ch][t];
    const float sym = __shfl(ws, ((t & 7) << 3) | (t >> 3));  // W^T partner
    const float v = ws + sym;
    xout[b * 64 + t] = v;
    float vmin = v, vmax = v;
    #pragma unroll
    for (int off = 32; off; off >>= 1) {
      vmin = fminf(vmin, __shfl_down(vmin, off));
      vmax = fmaxf(vmax, __shfl_down(vmax, off));
    }
    if (t == 0) { bmin[b] = vmin; bmax[b] = vmax; }
  }
}

// ---- kernel 2: tabulate f(x) at NT nodes; full fp32 MLP per node ----
__device__ __forceinline__ float dot128(const float* __restrict__ W,
                                        const float* __restrict__ act, int t) {
  const float4* w4 = (const float4*)(W + (size_t)t * 128);
  const float4* a4 = (const float4*)act;
  float acc = 0.0f;
  #pragma unroll
  for (int kq = 0; kq < 32; ++kq) {
    float4 w = w4[kq];
    float4 a = a4[kq];
    acc += w.x * a.x + w.y * a.y + w.z * a.z + w.w * a.w;
  }
  return acc;
}

__global__ __launch_bounds__(128)
void k_table(const float* __restrict__ ew, const float* __restrict__ eb,
             const float* __restrict__ mup, const float* __restrict__ lrp,
             const float* __restrict__ W1, const float* __restrict__ b1,
             const float* __restrict__ W2, const float* __restrict__ b2,
             const float* __restrict__ W3, const float* __restrict__ b3,
             const float* __restrict__ bmin, const float* __restrict__ bmax,
             float* __restrict__ mmf, float* __restrict__ table) {
  __shared__ __align__(16) float actA[128];
  __shared__ __align__(16) float actB[128];
  __shared__ float red[2];
  __shared__ float red2[2];
  const int t = threadIdx.x;
  const int wv = t >> 6;

  // reduce the per-block min/max arrays (1024 each, L2-resident)
  float mn = 1e30f, mx = -1e30f;
  #pragma unroll
  for (int i = 0; i < 8; ++i) {
    mn = fminf(mn, bmin[t + i * 128]);
    mx = fmaxf(mx, bmax[t + i * 128]);
  }
  #pragma unroll
  for (int off = 32; off; off >>= 1) {
    mn = fminf(mn, __shfl_xor(mn, off));
    mx = fmaxf(mx, __shfl_xor(mx, off));
  }
  if ((t & 63) == 0) { red[wv] = mn; red2[wv] = mx; }
  __syncthreads();
  const float xmin = fminf(red[0], red[1]);
  const float xmax = fmaxf(red2[0], red2[1]);
  if (blockIdx.x == 0 && t == 0) { mmf[0] = xmin; mmf[1] = xmax; }
  __syncthreads();

  const float x = xmin + (xmax - xmin) * ((float)blockIdx.x / (float)(NT - 1));

  // encoder softmax: e = softmax(ew*x + eb)
  float lg = ew[t] * x + eb[t];
  float m = lg;
  #pragma unroll
  for (int off = 32; off; off >>= 1) m = fmaxf(m, __shfl_xor(m, off));
  if ((t & 63) == 0) red[wv] = m;
  __syncthreads();
  m = fmaxf(red[0], red[1]);
  float ev = __expf(lg - m);
  float s = ev;
  #pragma unroll
  for (int off = 32; off; off >>= 1) s += __shfl_xor(s, off);
  if ((t & 63) == 0) red2[wv] = s;
  __syncthreads();
  s = red2[0] + red2[1];
  actA[t] = ev / s;
  __syncthreads();

  float h = fmaxf(b1[t] + dot128(W1, actA, t), 0.0f);
  actB[t] = h;
  __syncthreads();
  h = fmaxf(b2[t] + dot128(W2, actB, t), 0.0f);
  actA[t] = h;
  __syncthreads();
  float h3 = b3[t] + dot128(W3, actA, t);

  float m3 = h3;
  #pragma unroll
  for (int off = 32; off; off >>= 1) m3 = fmaxf(m3, __shfl_xor(m3, off));
  __syncthreads();
  if ((t & 63) == 0) red[wv] = m3;
  __syncthreads();
  m3 = fmaxf(red[0], red[1]);
  float e3 = __expf(h3 - m3);
  float dn = e3;
  float nm = e3 * mup[t];
  #pragma unroll
  for (int off = 32; off; off >>= 1) {
    dn += __shfl_xor(dn, off);
    nm += __shfl_xor(nm, off);
  }
  __syncthreads();
  if ((t & 63) == 0) { red[wv] = dn; red2[wv] = nm; }
  __syncthreads();
  if (t == 0)
    table[blockIdx.x] = lrp[0] * ((red2[0] + red2[1]) / (red[0] + red[1]));
}

// ---- kernel 3: linear interpolation of the table at each x ----
__global__ __launch_bounds__(256)
void k_interp(const float* __restrict__ xbuf, const float* __restrict__ table,
              const float* __restrict__ mmf, float* __restrict__ out, int n) {
  const int r = blockIdx.x * 256 + threadIdx.x;
  if (r >= n) return;
  const float xmin = mmf[0];
  const float xmax = mmf[1];
  const float range = xmax - xmin;
  const float scale = (range > 0.0f) ? (float)(NT - 1) / range : 0.0f;
  float p = (xbuf[r] - xmin) * scale;
  int i0 = (int)floorf(p);
  i0 = min(max(i0, 0), NT - 2);
  const float w = p - (float)i0;
  out[r] = table[i0] + w * (table[i0 + 1] - table[i0]);
}

extern "C" void kernel_launch(void* const* d_in, const int* in_sizes, int n_in,
                              void* d_out, int out_size, void* d_ws, size_t ws_size,
                              hipStream_t stream) {
  const float* pos  = (const float*)d_in[0];
  const float* cg   = (const float*)d_in[1];
  const float* sigp = (const float*)d_in[2];
  const float* ew   = (const float*)d_in[3];
  const float* eb   = (const float*)d_in[4];
  const float* mup  = (const float*)d_in[5];
  const float* lrp  = (const float*)d_in[6];
  const float* W1   = (const float*)d_in[7];
  const float* b1   = (const float*)d_in[8];
  const float* W2   = (const float*)d_in[9];
  const float* b2   = (const float*)d_in[10];
  const float* W3   = (const float*)d_in[11];
  const float* b3   = (const float*)d_in[12];
  float* out = (float*)d_out;

  // ws layout (floats): [0..15] header (mmf at 0,1), xbuf[65536], table[NT],
  // bmin[1024], bmax[1024], ctg[1944]
  float* mmf   = (float*)d_ws;
  float* xbuf  = (float*)d_ws + 16;
  float* table = xbuf + NOUT;
  float* bmin  = table + NT;
  float* bmax  = bmin + NBATCH;
  float* ctg   = bmax + NBATCH;

  k_prep<<<8, 256, 0, stream>>>(cg, ctg);
  k_ovl<<<NBATCH, 256, 0, stream>>>(pos, cg, sigp, ctg, xbuf, bmin, bmax);
  k_table<<<NT, 128, 0, stream>>>(ew, eb, mup, lrp, W1, b1, W2, b2, W3, b3,
                                  bmin, bmax, mmf, table);
  k_interp<<<(NOUT + 255) / 256, 256, 0, stream>>>(xbuf, table, mmf, out, NOUT);
}

// Round 11
// 39.886 us; speedup vs baseline: 10.4364x; 10.4364x over previous
//
#include <hip/hip_runtime.h>

#define NT 256          // f(x) table size
#define NBATCH 1024
#define NOUT 65536      // 1024*64

#if __has_builtin(__builtin_amdgcn_exp2f)
#define EXP2(x) __builtin_amdgcn_exp2f(x)
#else
#define EXP2(x) exp2f(x)
#endif

// ---- graph constants (baked from the reference) ----
__constant__ int c_e1[17] = {0,0,1,2,2,3,4,5,6,8,8,9,10,11,11,13,14};
__constant__ int c_e2[17] = {1,4,2,3,5,4,12,6,7,9,12,10,11,12,13,14,15};
__constant__ int c_p0[24] = {1,0,1,1,3,2,0,0,3,2,5,5,9,8,9,10,10,12,4,4,8,11,13,13};
__constant__ int c_p1[24] = {4,2,3,5,5,4,3,12,12,6,7,6,12,10,11,11,13,13,8,11,11,14,15,14};
__constant__ int c_ni[24] = {0,1,2,2,2,3,4,4,4,5,6,7,8,9,10,11,11,11,12,12,12,13,14,15};

// 6 unordered products (a<=b). E_ab symmetric => ovl = W + W^T,
// W = sum pref_ab * C_a E_ab C_b^T  (diagonal gets pref/2, folded into exp arg).
__constant__ int c_pa[6]   = {0,0,0,1,1,2};
__constant__ int c_pb[6]   = {0,1,2,1,2,2};
__constant__ int c_diag[6] = {1,0,0,1,0,1};

// ---- kernel 1: per-batch W; ovl = W + W^T ----
// PROVEN REGIME (r2/r3/r8/r9): 256 threads, two-phase V->stage2 through LDS,
// no LDS atomics, NAMED scalar accumulators only (arrays => scratch, r4-r7).
// r10 lesson: per-lane global loads of uniform data => not scalarized =>
// 571MB HBM + spill (416us). CT stays in LDS (broadcast reads are fine).
// v11: stage-2 register-blocked 4x4: 64 threads = (pg,qg)x16 i-chunks,
// b128 CT + b128 Vall per iter feed 16 fma (was 4 fma per b32+b128).
__global__ __launch_bounds__(256, 6)
void k_ovl(const float* __restrict__ pos, const float* __restrict__ cg,
           const float* __restrict__ sigp, float* __restrict__ xout,
           float* __restrict__ bmin, float* __restrict__ bmax) {
  // manual smem layout (floats): posS[48] | P4[81][4] | CT[3][81][8] |
  // Vall[6][81][8] | cInv[6] cLgp[6]   == 6216 floats = 24.9 KB
  __shared__ __align__(16) float smem[6216];
  float* posS          = smem;                               // [48]
  float (*P4)[4]       = (float(*)[4])   (smem + 48);        // [81][4]
  float (*CT)[81][8]   = (float(*)[81][8])(smem + 372);      // [3][81][8]
  float (*Vall)[81][8] = (float(*)[81][8])(smem + 2316);     // [6][81][8]
  float* cInv          = smem + 6204;                        // [6]
  float* cLgp          = smem + 6210;                        // [6]
  float (*red16)[65]   = (float(*)[65])  (smem + 2316);      // ALIAS of Vall:
  // [16][65] partials, written only after stage-2 reads finish (barrier).

  const int b = blockIdx.x;
  const int t = threadIdx.x;

  if (t < 48) posS[t] = pos[b * 48 + t];

  // make_opposite_blocks forward: odd cross cols (bp>=33, odd offset) = -C[:,col-1]
  for (int idx = t; idx < 3 * 81 * 8; idx += 256) {
    int s = idx / 648;
    int rem = idx - s * 648;
    int j = rem >> 3, q = rem & 7;
    int col = s * 81 + j;
    int off = j - 33;
    float v;
    if (off >= 0 && (off & 1)) v = -cg[q * 243 + (col - 1)];
    else                       v =  cg[q * 243 + col];
    CT[s][j][q] = v;
  }

  if (t == 0) {
    float sg[3];
    sg[0] = 0.4f * __expf(sigp[0]);
    sg[1] = 0.8f * __expf(sigp[1]);
    sg[2] = 1.2f * __expf(sigp[2]);
    #pragma unroll
    for (int p = 0; p < 6; ++p) {
      float sa = sg[c_pa[p]], sb = sg[c_pb[p]];
      float s2 = sa * sa + sb * sb;
      float rr = 2.0f * sa * sb / s2;
      cLgp[p] = 1.5f * __log2f(rr) - (float)c_diag[p];  // diag: pref/2
      cInv[p] = (-0.5f / s2) * 1.44269504088896f;       // includes log2(e)
    }
  }
  __syncthreads();

  // 81 block points: 16 atoms, 17 bond midpoints, 24 pairs x 2 cross points
  if (t < 81) {
    float x, y, z;
    if (t < 16) {
      x = posS[t * 3]; y = posS[t * 3 + 1]; z = posS[t * 3 + 2];
    } else if (t < 33) {
      int e = t - 16;
      int a0 = c_e1[e] * 3, a1 = c_e2[e] * 3;
      x = 0.5f * (posS[a0] + posS[a1]);
      y = 0.5f * (posS[a0 + 1] + posS[a1 + 1]);
      z = 0.5f * (posS[a0 + 2] + posS[a1 + 2]);
    } else {
      int k = (t - 33) >> 1, sgn = (t - 33) & 1;
      float sc = sgn ? 0.25f : -0.25f;
      int n = c_ni[k] * 3, a0 = c_p0[k] * 3, a1 = c_p1[k] * 3;
      x = posS[n]     + sc * (posS[a0]     - posS[a1]);
      y = posS[n + 1] + sc * (posS[a0 + 1] - posS[a1 + 1]);
      z = posS[n + 2] + sc * (posS[a0 + 2] - posS[a1 + 2]);
    }
    P4[t][0] = x; P4[t][1] = y; P4[t][2] = z;
    P4[t][3] = x * x + y * y + z * z;
  }
  __syncthreads();

  // ---- V phase: 162 tasks = (product s, 3-row strip of i) ----
  if (t < 162) {
    const int s = t / 27;
    const int i0 = (t - s * 27) * 3;
    const int bb = c_pb[s];
    const float nInv = cInv[s];
    const float lgp  = cLgp[s];

    const float4 pA = *(const float4*)P4[i0];
    const float4 pB = *(const float4*)P4[i0 + 1];
    const float4 pC = *(const float4*)P4[i0 + 2];
    const float cA = fmaf(pA.w, nInv, lgp);
    const float cB = fmaf(pB.w, nInv, lgp);
    const float cC = fmaf(pC.w, nInv, lgp);
    const float m2 = -2.0f * nInv;

    float v00=0,v01=0,v02=0,v03=0,v04=0,v05=0,v06=0,v07=0;
    float v10=0,v11=0,v12=0,v13=0,v14=0,v15=0,v16=0,v17=0;
    float v20=0,v21=0,v22=0,v23=0,v24=0,v25=0,v26=0,v27=0;

    // singles: atoms + bond midpoints (j = 0..32)
    #pragma unroll 3
    for (int j = 0; j < 33; ++j) {
      const float4 pj = *(const float4*)P4[j];
      const float rj = pj.w * nInv;
      const float dA = pA.x * pj.x + pA.y * pj.y + pA.z * pj.z;
      const float dB = pB.x * pj.x + pB.y * pj.y + pB.z * pj.z;
      const float dC = pC.x * pj.x + pC.y * pj.y + pC.z * pj.z;
      const float eA = EXP2(fmaf(m2, dA, cA + rj));
      const float eB = EXP2(fmaf(m2, dB, cB + rj));
      const float eC = EXP2(fmaf(m2, dC, cC + rj));
      const float4 cb0 = *(const float4*)&CT[bb][j][0];
      const float4 cb1 = *(const float4*)&CT[bb][j][4];
      v00 = fmaf(eA, cb0.x, v00); v01 = fmaf(eA, cb0.y, v01);
      v02 = fmaf(eA, cb0.z, v02); v03 = fmaf(eA, cb0.w, v03);
      v04 = fmaf(eA, cb1.x, v04); v05 = fmaf(eA, cb1.y, v05);
      v06 = fmaf(eA, cb1.z, v06); v07 = fmaf(eA, cb1.w, v07);
      v10 = fmaf(eB, cb0.x, v10); v11 = fmaf(eB, cb0.y, v11);
      v12 = fmaf(eB, cb0.z, v12); v13 = fmaf(eB, cb0.w, v13);
      v14 = fmaf(eB, cb1.x, v14); v15 = fmaf(eB, cb1.y, v15);
      v16 = fmaf(eB, cb1.z, v16); v17 = fmaf(eB, cb1.w, v17);
      v20 = fmaf(eC, cb0.x, v20); v21 = fmaf(eC, cb0.y, v21);
      v22 = fmaf(eC, cb0.z, v22); v23 = fmaf(eC, cb0.w, v23);
      v24 = fmaf(eC, cb1.x, v24); v25 = fmaf(eC, cb1.y, v25);
      v26 = fmaf(eC, cb1.z, v26); v27 = fmaf(eC, cb1.w, v27);
    }

    // cross-point pairs: j+ = 33+2k (ct), j- = j+ + 1 (-ct).
    // contribution = (e+ - e-) * ct  — one ct read per pair.
    for (int k = 0; k < 24; ++k) {
      const int jp = 33 + (k << 1);
      const float4 pp = *(const float4*)P4[jp];
      const float4 pm = *(const float4*)P4[jp + 1];
      const float rp = pp.w * nInv;
      const float rm = pm.w * nInv;
      const float dAp = pA.x * pp.x + pA.y * pp.y + pA.z * pp.z;
      const float dBp = pB.x * pp.x + pB.y * pp.y + pB.z * pp.z;
      const float dCp = pC.x * pp.x + pC.y * pp.y + pC.z * pp.z;
      const float dAm = pA.x * pm.x + pA.y * pm.y + pA.z * pm.z;
      const float dBm = pB.x * pm.x + pB.y * pm.y + pB.z * pm.z;
      const float dCm = pC.x * pm.x + pC.y * pm.y + pC.z * pm.z;
      const float gA = EXP2(fmaf(m2, dAp, cA + rp)) - EXP2(fmaf(m2, dAm, cA + rm));
      const float gB = EXP2(fmaf(m2, dBp, cB + rp)) - EXP2(fmaf(m2, dBm, cB + rm));
      const float gC = EXP2(fmaf(m2, dCp, cC + rp)) - EXP2(fmaf(m2, dCm, cC + rm));
      const float4 cb0 = *(const float4*)&CT[bb][jp][0];
      const float4 cb1 = *(const float4*)&CT[bb][jp][4];
      v00 = fmaf(gA, cb0.x, v00); v01 = fmaf(gA, cb0.y, v01);
      v02 = fmaf(gA, cb0.z, v02); v03 = fmaf(gA, cb0.w, v03);
      v04 = fmaf(gA, cb1.x, v04); v05 = fmaf(gA, cb1.y, v05);
      v06 = fmaf(gA, cb1.z, v06); v07 = fmaf(gA, cb1.w, v07);
      v10 = fmaf(gB, cb0.x, v10); v11 = fmaf(gB, cb0.y, v11);
      v12 = fmaf(gB, cb0.z, v12); v13 = fmaf(gB, cb0.w, v13);
      v14 = fmaf(gB, cb1.x, v14); v15 = fmaf(gB, cb1.y, v15);
      v16 = fmaf(gB, cb1.z, v16); v17 = fmaf(gB, cb1.w, v17);
      v20 = fmaf(gC, cb0.x, v20); v21 = fmaf(gC, cb0.y, v21);
      v22 = fmaf(gC, cb0.z, v22); v23 = fmaf(gC, cb0.w, v23);
      v24 = fmaf(gC, cb1.x, v24); v25 = fmaf(gC, cb1.y, v25);
      v26 = fmaf(gC, cb1.z, v26); v27 = fmaf(gC, cb1.w, v27);
    }

    float4* vo = (float4*)&Vall[s][i0][0];
    vo[0] = make_float4(v00, v01, v02, v03);
    vo[1] = make_float4(v04, v05, v06, v07);
    vo[2] = make_float4(v10, v11, v12, v13);
    vo[3] = make_float4(v14, v15, v16, v17);
    vo[4] = make_float4(v20, v21, v22, v23);
    vo[5] = make_float4(v24, v25, v26, v27);
  }
  __syncthreads();

  // ---- stage 2 (register-blocked 4x4): W[p][q] = sum_s sum_i CT*Vall ----
  // 64 threads: combo = t>>4 => pg=combo>>1, qg=combo&1; ch = t&15 (i-chunk).
  // Per iter: b128 CT (4 p's) + b128 Vall (4 q's) -> 16 fma. 16 NAMED scalars.
  float w00=0,w01=0,w02=0,w03=0, w10=0,w11=0,w12=0,w13=0;
  float w20=0,w21=0,w22=0,w23=0, w30=0,w31=0,w32=0,w33=0;
  const int ch = t & 15;
  if (t < 64) {
    const int pg = (t >> 5) & 1;
    const int qg = (t >> 4) & 1;
    const int ib = ch * 5;
    const int ie = (ch == 15) ? 81 : ib + 5;
    #pragma unroll
    for (int s = 0; s < 6; ++s) {
      const int lf = c_pa[s];
      for (int i = ib; i < ie; ++i) {
        const float4 ct = *(const float4*)&CT[lf][i][pg * 4];
        const float4 vv = *(const float4*)&Vall[s][i][qg * 4];
        w00 = fmaf(ct.x, vv.x, w00); w01 = fmaf(ct.x, vv.y, w01);
        w02 = fmaf(ct.x, vv.z, w02); w03 = fmaf(ct.x, vv.w, w03);
        w10 = fmaf(ct.y, vv.x, w10); w11 = fmaf(ct.y, vv.y, w11);
        w12 = fmaf(ct.y, vv.z, w12); w13 = fmaf(ct.y, vv.w, w13);
        w20 = fmaf(ct.z, vv.x, w20); w21 = fmaf(ct.z, vv.y, w21);
        w22 = fmaf(ct.z, vv.z, w22); w23 = fmaf(ct.z, vv.w, w23);
        w30 = fmaf(ct.w, vv.x, w30); w31 = fmaf(ct.w, vv.y, w31);
        w32 = fmaf(ct.w, vv.z, w32); w33 = fmaf(ct.w, vv.w, w33);
      }
    }
  }
  __syncthreads();   // all Vall/CT stage-2 reads done; red16 (alias) writable
  if (t < 64) {
    const int pg = (t >> 5) & 1;
    const int qg = (t >> 4) & 1;
    const int base = pg * 32 + qg * 4;
    red16[ch][base + 0 * 8 + 0] = w00; red16[ch][base + 0 * 8 + 1] = w01;
    red16[ch][base + 0 * 8 + 2] = w02; red16[ch][base + 0 * 8 + 3] = w03;
    red16[ch][base + 1 * 8 + 0] = w10; red16[ch][base + 1 * 8 + 1] = w11;
    red16[ch][base + 1 * 8 + 2] = w12; red16[ch][base + 1 * 8 + 3] = w13;
    red16[ch][base + 2 * 8 + 0] = w20; red16[ch][base + 2 * 8 + 1] = w21;
    red16[ch][base + 2 * 8 + 2] = w22; red16[ch][base + 2 * 8 + 3] = w23;
    red16[ch][base + 3 * 8 + 0] = w30; red16[ch][base + 3 * 8 + 1] = w31;
    red16[ch][base + 3 * 8 + 2] = w32; red16[ch][base + 3 * 8 + 3] = w33;
  }
  __syncthreads();

  if (t < 64) {
    float ws = 0.0f;
    #pragma unroll
    for (int c = 0; c < 16; ++c) ws += red16[c][t];
    const float sym = __shfl(ws, ((t & 7) << 3) | (t >> 3));  // W^T partner
    const float v = ws + sym;
    xout[b * 64 + t] = v;
    float vmin = v, vmax = v;
    #pragma unroll
    for (int off = 32; off; off >>= 1) {
      vmin = fminf(vmin, __shfl_down(vmin, off));
      vmax = fmaxf(vmax, __shfl_down(vmax, off));
    }
    if (t == 0) { bmin[b] = vmin; bmax[b] = vmax; }
  }
}

// ---- kernel 2: tabulate f(x) at NT nodes; full fp32 MLP per node ----
__device__ __forceinline__ float dot128(const float* __restrict__ W,
                                        const float* __restrict__ act, int t) {
  const float4* w4 = (const float4*)(W + (size_t)t * 128);
  const float4* a4 = (const float4*)act;
  float acc = 0.0f;
  #pragma unroll
  for (int kq = 0; kq < 32; ++kq) {
    float4 w = w4[kq];
    float4 a = a4[kq];
    acc += w.x * a.x + w.y * a.y + w.z * a.z + w.w * a.w;
  }
  return acc;
}

__global__ __launch_bounds__(128)
void k_table(const float* __restrict__ ew, const float* __restrict__ eb,
             const float* __restrict__ mup, const float* __restrict__ lrp,
             const float* __restrict__ W1, const float* __restrict__ b1,
             const float* __restrict__ W2, const float* __restrict__ b2,
             const float* __restrict__ W3, const float* __restrict__ b3,
             const float* __restrict__ bmin, const float* __restrict__ bmax,
             float* __restrict__ mmf, float* __restrict__ table) {
  __shared__ __align__(16) float actA[128];
  __shared__ __align__(16) float actB[128];
  __shared__ float red[2];
  __shared__ float red2[2];
  const int t = threadIdx.x;
  const int wv = t >> 6;

  // reduce the per-block min/max arrays (1024 each, L2-resident)
  float mn = 1e30f, mx = -1e30f;
  #pragma unroll
  for (int i = 0; i < 8; ++i) {
    mn = fminf(mn, bmin[t + i * 128]);
    mx = fmaxf(mx, bmax[t + i * 128]);
  }
  #pragma unroll
  for (int off = 32; off; off >>= 1) {
    mn = fminf(mn, __shfl_xor(mn, off));
    mx = fmaxf(mx, __shfl_xor(mx, off));
  }
  if ((t & 63) == 0) { red[wv] = mn; red2[wv] = mx; }
  __syncthreads();
  const float xmin = fminf(red[0], red[1]);
  const float xmax = fmaxf(red2[0], red2[1]);
  if (blockIdx.x == 0 && t == 0) { mmf[0] = xmin; mmf[1] = xmax; }
  __syncthreads();

  const float x = xmin + (xmax - xmin) * ((float)blockIdx.x / (float)(NT - 1));

  // encoder softmax: e = softmax(ew*x + eb)
  float lg = ew[t] * x + eb[t];
  float m = lg;
  #pragma unroll
  for (int off = 32; off; off >>= 1) m = fmaxf(m, __shfl_xor(m, off));
  if ((t & 63) == 0) red[wv] = m;
  __syncthreads();
  m = fmaxf(red[0], red[1]);
  float ev = __expf(lg - m);
  float s = ev;
  #pragma unroll
  for (int off = 32; off; off >>= 1) s += __shfl_xor(s, off);
  if ((t & 63) == 0) red2[wv] = s;
  __syncthreads();
  s = red2[0] + red2[1];
  actA[t] = ev / s;
  __syncthreads();

  float h = fmaxf(b1[t] + dot128(W1, actA, t), 0.0f);
  actB[t] = h;
  __syncthreads();
  h = fmaxf(b2[t] + dot128(W2, actB, t), 0.0f);
  actA[t] = h;
  __syncthreads();
  float h3 = b3[t] + dot128(W3, actA, t);

  float m3 = h3;
  #pragma unroll
  for (int off = 32; off; off >>= 1) m3 = fmaxf(m3, __shfl_xor(m3, off));
  __syncthreads();
  if ((t & 63) == 0) red[wv] = m3;
  __syncthreads();
  m3 = fmaxf(red[0], red[1]);
  float e3 = __expf(h3 - m3);
  float dn = e3;
  float nm = e3 * mup[t];
  #pragma unroll
  for (int off = 32; off; off >>= 1) {
    dn += __shfl_xor(dn, off);
    nm += __shfl_xor(nm, off);
  }
  __syncthreads();
  if ((t & 63) == 0) { red[wv] = dn; red2[wv] = nm; }
  __syncthreads();
  if (t == 0)
    table[blockIdx.x] = lrp[0] * ((red2[0] + red2[1]) / (red[0] + red[1]));
}

// ---- kernel 3: linear interpolation of the table at each x ----
__global__ __launch_bounds__(256)
void k_interp(const float* __restrict__ xbuf, const float* __restrict__ table,
              const float* __restrict__ mmf, float* __restrict__ out, int n) {
  const int r = blockIdx.x * 256 + threadIdx.x;
  if (r >= n) return;
  const float xmin = mmf[0];
  const float xmax = mmf[1];
  const float range = xmax - xmin;
  const float scale = (range > 0.0f) ? (float)(NT - 1) / range : 0.0f;
  float p = (xbuf[r] - xmin) * scale;
  int i0 = (int)floorf(p);
  i0 = min(max(i0, 0), NT - 2);
  const float w = p - (float)i0;
  out[r] = table[i0] + w * (table[i0 + 1] - table[i0]);
}

extern "C" void kernel_launch(void* const* d_in, const int* in_sizes, int n_in,
                              void* d_out, int out_size, void* d_ws, size_t ws_size,
                              hipStream_t stream) {
  const float* pos  = (const float*)d_in[0];
  const float* cg   = (const float*)d_in[1];
  const float* sigp = (const float*)d_in[2];
  const float* ew   = (const float*)d_in[3];
  const float* eb   = (const float*)d_in[4];
  const float* mup  = (const float*)d_in[5];
  const float* lrp  = (const float*)d_in[6];
  const float* W1   = (const float*)d_in[7];
  const float* b1   = (const float*)d_in[8];
  const float* W2   = (const float*)d_in[9];
  const float* b2   = (const float*)d_in[10];
  const float* W3   = (const float*)d_in[11];
  const float* b3   = (const float*)d_in[12];
  float* out = (float*)d_out;

  // ws layout (floats): [0..15] header (mmf at 0,1), xbuf[65536], table[NT],
  // bmin[1024], bmax[1024]
  float* mmf   = (float*)d_ws;
  float* xbuf  = (float*)d_ws + 16;
  float* table = xbuf + NOUT;
  float* bmin  = table + NT;
  float* bmax  = bmin + NBATCH;

  k_ovl<<<NBATCH, 256, 0, stream>>>(pos, cg, sigp, xbuf, bmin, bmax);
  k_table<<<NT, 128, 0, stream>>>(ew, eb, mup, lrp, W1, b1, W2, b2, W3, b3,
                                  bmin, bmax, mmf, table);
  k_interp<<<(NOUT + 255) / 256, 256, 0, stream>>>(xbuf, table, mmf, out, NOUT);
}

// Round 12
// 38.604 us; speedup vs baseline: 10.7830x; 1.0332x over previous
//
#include <hip/hip_runtime.h>

#define NT 256          // f(x) table size
#define NBATCH 1024
#define NOUT 65536      // 1024*64

#if __has_builtin(__builtin_amdgcn_exp2f)
#define EXP2(x) __builtin_amdgcn_exp2f(x)
#else
#define EXP2(x) exp2f(x)
#endif

// ---- graph constants (baked from the reference) ----
__constant__ int c_e1[17] = {0,0,1,2,2,3,4,5,6,8,8,9,10,11,11,13,14};
__constant__ int c_e2[17] = {1,4,2,3,5,4,12,6,7,9,12,10,11,12,13,14,15};
__constant__ int c_p0[24] = {1,0,1,1,3,2,0,0,3,2,5,5,9,8,9,10,10,12,4,4,8,11,13,13};
__constant__ int c_p1[24] = {4,2,3,5,5,4,3,12,12,6,7,6,12,10,11,11,13,13,8,11,11,14,15,14};
__constant__ int c_ni[24] = {0,1,2,2,2,3,4,4,4,5,6,7,8,9,10,11,11,11,12,12,12,13,14,15};

// 6 unordered products (a<=b). E_ab symmetric => ovl = W + W^T,
// W = sum pref_ab * C_a E_ab C_b^T  (diagonal gets pref/2, folded into exp arg).
__constant__ int c_pa[6]   = {0,0,0,1,1,2};
__constant__ int c_pb[6]   = {0,1,2,1,2,2};
__constant__ int c_diag[6] = {1,0,0,1,0,1};

// ---- kernel 1: per-batch W; ovl = W + W^T ----
// PROVEN REGIME (r2/r3/r8/r9/r11): 256 threads, two-phase V->stage2 through
// LDS, no LDS atomics, NAMED scalar accumulators only (arrays => scratch,
// r4-r7; per-lane "uniform" global loads => 571MB HBM, r10).
// v12: V-phase latency attack — r9/r11 showed instruction-count cuts give
// only ~1us each => stall-bound at 2.53 active waves (162 tasks). 2-row
// strips: 6 products x 41 strips = 246 tasks, 96% of 256 threads, all 4
// waves active, 16 named accumulators (proven <=24 limit).
__global__ __launch_bounds__(256, 6)
void k_ovl(const float* __restrict__ pos, const float* __restrict__ cg,
           const float* __restrict__ sigp, float* __restrict__ xout,
           float* __restrict__ bmin, float* __restrict__ bmax) {
  // manual smem layout (floats): posS[48] | P4[81][4] | CT[3][81][8] |
  // Vall[6][81][8] | cInv[6] cLgp[6]   == 6216 floats = 24.9 KB
  __shared__ __align__(16) float smem[6216];
  float* posS          = smem;                               // [48]
  float (*P4)[4]       = (float(*)[4])   (smem + 48);        // [81][4]
  float (*CT)[81][8]   = (float(*)[81][8])(smem + 372);      // [3][81][8]
  float (*Vall)[81][8] = (float(*)[81][8])(smem + 2316);     // [6][81][8]
  float* cInv          = smem + 6204;                        // [6]
  float* cLgp          = smem + 6210;                        // [6]
  float (*red16)[65]   = (float(*)[65])  (smem + 2316);      // ALIAS of Vall:
  // [16][65] partials, written only after stage-2 reads finish (barrier).

  const int b = blockIdx.x;
  const int t = threadIdx.x;

  if (t < 48) posS[t] = pos[b * 48 + t];

  // make_opposite_blocks forward: odd cross cols (bp>=33, odd offset) = -C[:,col-1]
  for (int idx = t; idx < 3 * 81 * 8; idx += 256) {
    int s = idx / 648;
    int rem = idx - s * 648;
    int j = rem >> 3, q = rem & 7;
    int col = s * 81 + j;
    int off = j - 33;
    float v;
    if (off >= 0 && (off & 1)) v = -cg[q * 243 + (col - 1)];
    else                       v =  cg[q * 243 + col];
    CT[s][j][q] = v;
  }

  if (t == 0) {
    float sg[3];
    sg[0] = 0.4f * __expf(sigp[0]);
    sg[1] = 0.8f * __expf(sigp[1]);
    sg[2] = 1.2f * __expf(sigp[2]);
    #pragma unroll
    for (int p = 0; p < 6; ++p) {
      float sa = sg[c_pa[p]], sb = sg[c_pb[p]];
      float s2 = sa * sa + sb * sb;
      float rr = 2.0f * sa * sb / s2;
      cLgp[p] = 1.5f * __log2f(rr) - (float)c_diag[p];  // diag: pref/2
      cInv[p] = (-0.5f / s2) * 1.44269504088896f;       // includes log2(e)
    }
  }
  __syncthreads();

  // 81 block points: 16 atoms, 17 bond midpoints, 24 pairs x 2 cross points
  if (t < 81) {
    float x, y, z;
    if (t < 16) {
      x = posS[t * 3]; y = posS[t * 3 + 1]; z = posS[t * 3 + 2];
    } else if (t < 33) {
      int e = t - 16;
      int a0 = c_e1[e] * 3, a1 = c_e2[e] * 3;
      x = 0.5f * (posS[a0] + posS[a1]);
      y = 0.5f * (posS[a0 + 1] + posS[a1 + 1]);
      z = 0.5f * (posS[a0 + 2] + posS[a1 + 2]);
    } else {
      int k = (t - 33) >> 1, sgn = (t - 33) & 1;
      float sc = sgn ? 0.25f : -0.25f;
      int n = c_ni[k] * 3, a0 = c_p0[k] * 3, a1 = c_p1[k] * 3;
      x = posS[n]     + sc * (posS[a0]     - posS[a1]);
      y = posS[n + 1] + sc * (posS[a0 + 1] - posS[a1 + 1]);
      z = posS[n + 2] + sc * (posS[a0 + 2] - posS[a1 + 2]);
    }
    P4[t][0] = x; P4[t][1] = y; P4[t][2] = z;
    P4[t][3] = x * x + y * y + z * z;
  }
  __syncthreads();

  // ---- V phase: 246 tasks = (product s, 2-row strip); strip 40 = 1 row ----
  if (t < 246) {
    const int s = t / 41;
    const int st = t - s * 41;
    const int i0 = st * 2;
    const bool two = (st < 40);           // last strip: single row (i0==80)
    const int i1 = two ? i0 + 1 : i0;     // duplicate row if single (no OOB)
    const int bb = c_pb[s];
    const float nInv = cInv[s];
    const float lgp  = cLgp[s];

    const float4 pA = *(const float4*)P4[i0];
    const float4 pB = *(const float4*)P4[i1];
    const float cA = fmaf(pA.w, nInv, lgp);
    const float cB = fmaf(pB.w, nInv, lgp);
    const float m2 = -2.0f * nInv;

    float v00=0,v01=0,v02=0,v03=0,v04=0,v05=0,v06=0,v07=0;
    float v10=0,v11=0,v12=0,v13=0,v14=0,v15=0,v16=0,v17=0;

    // singles: atoms + bond midpoints (j = 0..32)
    #pragma unroll 3
    for (int j = 0; j < 33; ++j) {
      const float4 pj = *(const float4*)P4[j];
      const float rj = pj.w * nInv;
      const float dA = pA.x * pj.x + pA.y * pj.y + pA.z * pj.z;
      const float dB = pB.x * pj.x + pB.y * pj.y + pB.z * pj.z;
      const float eA = EXP2(fmaf(m2, dA, cA + rj));
      const float eB = EXP2(fmaf(m2, dB, cB + rj));
      const float4 cb0 = *(const float4*)&CT[bb][j][0];
      const float4 cb1 = *(const float4*)&CT[bb][j][4];
      v00 = fmaf(eA, cb0.x, v00); v01 = fmaf(eA, cb0.y, v01);
      v02 = fmaf(eA, cb0.z, v02); v03 = fmaf(eA, cb0.w, v03);
      v04 = fmaf(eA, cb1.x, v04); v05 = fmaf(eA, cb1.y, v05);
      v06 = fmaf(eA, cb1.z, v06); v07 = fmaf(eA, cb1.w, v07);
      v10 = fmaf(eB, cb0.x, v10); v11 = fmaf(eB, cb0.y, v11);
      v12 = fmaf(eB, cb0.z, v12); v13 = fmaf(eB, cb0.w, v13);
      v14 = fmaf(eB, cb1.x, v14); v15 = fmaf(eB, cb1.y, v15);
      v16 = fmaf(eB, cb1.z, v16); v17 = fmaf(eB, cb1.w, v17);
    }

    // cross-point pairs: j+ = 33+2k (ct), j- = j+ + 1 (-ct).
    // contribution = (e+ - e-) * ct  — one ct read per pair.
    for (int k = 0; k < 24; ++k) {
      const int jp = 33 + (k << 1);
      const float4 pp = *(const float4*)P4[jp];
      const float4 pm = *(const float4*)P4[jp + 1];
      const float rp = pp.w * nInv;
      const float rm = pm.w * nInv;
      const float dAp = pA.x * pp.x + pA.y * pp.y + pA.z * pp.z;
      const float dBp = pB.x * pp.x + pB.y * pp.y + pB.z * pp.z;
      const float dAm = pA.x * pm.x + pA.y * pm.y + pA.z * pm.z;
      const float dBm = pB.x * pm.x + pB.y * pm.y + pB.z * pm.z;
      const float gA = EXP2(fmaf(m2, dAp, cA + rp)) - EXP2(fmaf(m2, dAm, cA + rm));
      const float gB = EXP2(fmaf(m2, dBp, cB + rp)) - EXP2(fmaf(m2, dBm, cB + rm));
      const float4 cb0 = *(const float4*)&CT[bb][jp][0];
      const float4 cb1 = *(const float4*)&CT[bb][jp][4];
      v00 = fmaf(gA, cb0.x, v00); v01 = fmaf(gA, cb0.y, v01);
      v02 = fmaf(gA, cb0.z, v02); v03 = fmaf(gA, cb0.w, v03);
      v04 = fmaf(gA, cb1.x, v04); v05 = fmaf(gA, cb1.y, v05);
      v06 = fmaf(gA, cb1.z, v06); v07 = fmaf(gA, cb1.w, v07);
      v10 = fmaf(gB, cb0.x, v10); v11 = fmaf(gB, cb0.y, v11);
      v12 = fmaf(gB, cb0.z, v12); v13 = fmaf(gB, cb0.w, v13);
      v14 = fmaf(gB, cb1.x, v14); v15 = fmaf(gB, cb1.y, v15);
      v16 = fmaf(gB, cb1.z, v16); v17 = fmaf(gB, cb1.w, v17);
    }

    float4* vo = (float4*)&Vall[s][i0][0];
    vo[0] = make_float4(v00, v01, v02, v03);
    vo[1] = make_float4(v04, v05, v06, v07);
    if (two) {
      vo[2] = make_float4(v10, v11, v12, v13);
      vo[3] = make_float4(v14, v15, v16, v17);
    }
  }
  __syncthreads();

  // ---- stage 2 (register-blocked 4x4): W[p][q] = sum_s sum_i CT*Vall ----
  // 64 threads: pg=(t>>5)&1, qg=(t>>4)&1, ch=t&15 (i-chunk).
  // Per iter: b128 CT (4 p's) + b128 Vall (4 q's) -> 16 fma. 16 NAMED scalars.
  float w00=0,w01=0,w02=0,w03=0, w10=0,w11=0,w12=0,w13=0;
  float w20=0,w21=0,w22=0,w23=0, w30=0,w31=0,w32=0,w33=0;
  const int ch = t & 15;
  if (t < 64) {
    const int pg = (t >> 5) & 1;
    const int qg = (t >> 4) & 1;
    const int ib = ch * 5;
    const int ie = (ch == 15) ? 81 : ib + 5;
    #pragma unroll
    for (int s = 0; s < 6; ++s) {
      const int lf = c_pa[s];
      for (int i = ib; i < ie; ++i) {
        const float4 ct = *(const float4*)&CT[lf][i][pg * 4];
        const float4 vv = *(const float4*)&Vall[s][i][qg * 4];
        w00 = fmaf(ct.x, vv.x, w00); w01 = fmaf(ct.x, vv.y, w01);
        w02 = fmaf(ct.x, vv.z, w02); w03 = fmaf(ct.x, vv.w, w03);
        w10 = fmaf(ct.y, vv.x, w10); w11 = fmaf(ct.y, vv.y, w11);
        w12 = fmaf(ct.y, vv.z, w12); w13 = fmaf(ct.y, vv.w, w13);
        w20 = fmaf(ct.z, vv.x, w20); w21 = fmaf(ct.z, vv.y, w21);
        w22 = fmaf(ct.z, vv.z, w22); w23 = fmaf(ct.z, vv.w, w23);
        w30 = fmaf(ct.w, vv.x, w30); w31 = fmaf(ct.w, vv.y, w31);
        w32 = fmaf(ct.w, vv.z, w32); w33 = fmaf(ct.w, vv.w, w33);
      }
    }
  }
  __syncthreads();   // all Vall/CT stage-2 reads done; red16 (alias) writable
  if (t < 64) {
    const int pg = (t >> 5) & 1;
    const int qg = (t >> 4) & 1;
    const int base = pg * 32 + qg * 4;
    red16[ch][base + 0 * 8 + 0] = w00; red16[ch][base + 0 * 8 + 1] = w01;
    red16[ch][base + 0 * 8 + 2] = w02; red16[ch][base + 0 * 8 + 3] = w03;
    red16[ch][base + 1 * 8 + 0] = w10; red16[ch][base + 1 * 8 + 1] = w11;
    red16[ch][base + 1 * 8 + 2] = w12; red16[ch][base + 1 * 8 + 3] = w13;
    red16[ch][base + 2 * 8 + 0] = w20; red16[ch][base + 2 * 8 + 1] = w21;
    red16[ch][base + 2 * 8 + 2] = w22; red16[ch][base + 2 * 8 + 3] = w23;
    red16[ch][base + 3 * 8 + 0] = w30; red16[ch][base + 3 * 8 + 1] = w31;
    red16[ch][base + 3 * 8 + 2] = w32; red16[ch][base + 3 * 8 + 3] = w33;
  }
  __syncthreads();

  if (t < 64) {
    float ws = 0.0f;
    #pragma unroll
    for (int c = 0; c < 16; ++c) ws += red16[c][t];
    const float sym = __shfl(ws, ((t & 7) << 3) | (t >> 3));  // W^T partner
    const float v = ws + sym;
    xout[b * 64 + t] = v;
    float vmin = v, vmax = v;
    #pragma unroll
    for (int off = 32; off; off >>= 1) {
      vmin = fminf(vmin, __shfl_down(vmin, off));
      vmax = fmaxf(vmax, __shfl_down(vmax, off));
    }
    if (t == 0) { bmin[b] = vmin; bmax[b] = vmax; }
  }
}

// ---- kernel 2: tabulate f(x) at NT nodes; full fp32 MLP per node ----
__device__ __forceinline__ float dot128(const float* __restrict__ W,
                                        const float* __restrict__ act, int t) {
  const float4* w4 = (const float4*)(W + (size_t)t * 128);
  const float4* a4 = (const float4*)act;
  float acc = 0.0f;
  #pragma unroll
  for (int kq = 0; kq < 32; ++kq) {
    float4 w = w4[kq];
    float4 a = a4[kq];
    acc += w.x * a.x + w.y * a.y + w.z * a.z + w.w * a.w;
  }
  return acc;
}

__global__ __launch_bounds__(128)
void k_table(const float* __restrict__ ew, const float* __restrict__ eb,
             const float* __restrict__ mup, const float* __restrict__ lrp,
             const float* __restrict__ W1, const float* __restrict__ b1,
             const float* __restrict__ W2, const float* __restrict__ b2,
             const float* __restrict__ W3, const float* __restrict__ b3,
             const float* __restrict__ bmin, const float* __restrict__ bmax,
             float* __restrict__ mmf, float* __restrict__ table) {
  __shared__ __align__(16) float actA[128];
  __shared__ __align__(16) float actB[128];
  __shared__ float red[2];
  __shared__ float red2[2];
  const int t = threadIdx.x;
  const int wv = t >> 6;

  // reduce the per-block min/max arrays (1024 each, L2-resident)
  float mn = 1e30f, mx = -1e30f;
  #pragma unroll
  for (int i = 0; i < 8; ++i) {
    mn = fminf(mn, bmin[t + i * 128]);
    mx = fmaxf(mx, bmax[t + i * 128]);
  }
  #pragma unroll
  for (int off = 32; off; off >>= 1) {
    mn = fminf(mn, __shfl_xor(mn, off));
    mx = fmaxf(mx, __shfl_xor(mx, off));
  }
  if ((t & 63) == 0) { red[wv] = mn; red2[wv] = mx; }
  __syncthreads();
  const float xmin = fminf(red[0], red[1]);
  const float xmax = fmaxf(red2[0], red2[1]);
  if (blockIdx.x == 0 && t == 0) { mmf[0] = xmin; mmf[1] = xmax; }
  __syncthreads();

  const float x = xmin + (xmax - xmin) * ((float)blockIdx.x / (float)(NT - 1));

  // encoder softmax: e = softmax(ew*x + eb)
  float lg = ew[t] * x + eb[t];
  float m = lg;
  #pragma unroll
  for (int off = 32; off; off >>= 1) m = fmaxf(m, __shfl_xor(m, off));
  if ((t & 63) == 0) red[wv] = m;
  __syncthreads();
  m = fmaxf(red[0], red[1]);
  float ev = __expf(lg - m);
  float s = ev;
  #pragma unroll
  for (int off = 32; off; off >>= 1) s += __shfl_xor(s, off);
  if ((t & 63) == 0) red2[wv] = s;
  __syncthreads();
  s = red2[0] + red2[1];
  actA[t] = ev / s;
  __syncthreads();

  float h = fmaxf(b1[t] + dot128(W1, actA, t), 0.0f);
  actB[t] = h;
  __syncthreads();
  h = fmaxf(b2[t] + dot128(W2, actB, t), 0.0f);
  actA[t] = h;
  __syncthreads();
  float h3 = b3[t] + dot128(W3, actA, t);

  float m3 = h3;
  #pragma unroll
  for (int off = 32; off; off >>= 1) m3 = fmaxf(m3, __shfl_xor(m3, off));
  __syncthreads();
  if ((t & 63) == 0) red[wv] = m3;
  __syncthreads();
  m3 = fmaxf(red[0], red[1]);
  float e3 = __expf(h3 - m3);
  float dn = e3;
  float nm = e3 * mup[t];
  #pragma unroll
  for (int off = 32; off; off >>= 1) {
    dn += __shfl_xor(dn, off);
    nm += __shfl_xor(nm, off);
  }
  __syncthreads();
  if ((t & 63) == 0) { red[wv] = dn; red2[wv] = nm; }
  __syncthreads();
  if (t == 0)
    table[blockIdx.x] = lrp[0] * ((red2[0] + red2[1]) / (red[0] + red[1]));
}

// ---- kernel 3: linear interpolation of the table at each x ----
__global__ __launch_bounds__(256)
void k_interp(const float* __restrict__ xbuf, const float* __restrict__ table,
              const float* __restrict__ mmf, float* __restrict__ out, int n) {
  const int r = blockIdx.x * 256 + threadIdx.x;
  if (r >= n) return;
  const float xmin = mmf[0];
  const float xmax = mmf[1];
  const float range = xmax - xmin;
  const float scale = (range > 0.0f) ? (float)(NT - 1) / range : 0.0f;
  float p = (xbuf[r] - xmin) * scale;
  int i0 = (int)floorf(p);
  i0 = min(max(i0, 0), NT - 2);
  const float w = p - (float)i0;
  out[r] = table[i0] + w * (table[i0 + 1] - table[i0]);
}

extern "C" void kernel_launch(void* const* d_in, const int* in_sizes, int n_in,
                              void* d_out, int out_size, void* d_ws, size_t ws_size,
                              hipStream_t stream) {
  const float* pos  = (const float*)d_in[0];
  const float* cg   = (const float*)d_in[1];
  const float* sigp = (const float*)d_in[2];
  const float* ew   = (const float*)d_in[3];
  const float* eb   = (const float*)d_in[4];
  const float* mup  = (const float*)d_in[5];
  const float* lrp  = (const float*)d_in[6];
  const float* W1   = (const float*)d_in[7];
  const float* b1   = (const float*)d_in[8];
  const float* W2   = (const float*)d_in[9];
  const float* b2   = (const float*)d_in[10];
  const float* W3   = (const float*)d_in[11];
  const float* b3   = (const float*)d_in[12];
  float* out = (float*)d_out;

  // ws layout (floats): [0..15] header (mmf at 0,1), xbuf[65536], table[NT],
  // bmin[1024], bmax[1024]
  float* mmf   = (float*)d_ws;
  float* xbuf  = (float*)d_ws + 16;
  float* table = xbuf + NOUT;
  float* bmin  = table + NT;
  float* bmax  = bmin + NBATCH;

  k_ovl<<<NBATCH, 256, 0, stream>>>(pos, cg, sigp, xbuf, bmin, bmax);
  k_table<<<NT, 128, 0, stream>>>(ew, eb, mup, lrp, W1, b1, W2, b2, W3, b3,
                                  bmin, bmax, mmf, table);
  k_interp<<<(NOUT + 255) / 256, 256, 0, stream>>>(xbuf, table, mmf, out, NOUT);
}